// Round 6
// baseline (651.382 us; speedup 1.0000x reference)
//
#include <hip/hip_runtime.h>
#include <cstdint>
#include <cstddef>

// SwinBlock3D: LN1 -> roll(-1,-3,-3) -> window(2,7,7) attn (12 heads, rel-bias)
// -> proj + resid -> LN2 -> MLP(384->1536 gelu ->384) + resid.
// bf16 MFMA matmuls; fp32 LN/softmax/residuals.
// GEMM: A staged via global_load_lds (dbuf, counted vmcnt); B (weights, all
// L2-resident: 0.3-1.2MB) read DIRECTLY from global into regs -> halves LDS
// pipe traffic (was reads+DMA ~2260cyc vs 1242 MFMA per CU-tile in R4).

typedef __bf16 bf16x8 __attribute__((ext_vector_type(8)));
typedef __bf16 bf16x4 __attribute__((ext_vector_type(4)));
typedef float f32x4 __attribute__((ext_vector_type(4)));

#define DIM 384
#define QKV_DIM 1152
#define HID 1536
#define NHEADS 12
#define NTOK 50176
#define NWIN 512

// async global->LDS, 16B per lane; LDS dest = wave-uniform base + lane*16
__device__ __forceinline__ void gload16(const void* g, void* s) {
  __builtin_amdgcn_global_load_lds(
      (const __attribute__((address_space(1))) void*)g,
      (__attribute__((address_space(3))) void*)s, 16, 0, 0);
}

// ---------------- prep kernels ----------------
__global__ __launch_bounds__(256) void build_tokmap_k(int* __restrict__ map) {
  int t = blockIdx.x * 256 + threadIdx.x;
  if (t >= NTOK) return;
  int win = t / 98, n = t - win * 98;
  int b = win >> 8, tw = (win >> 6) & 3, hw = (win >> 3) & 7, ww = win & 7;
  int dt = n / 49; int rem = n - dt * 49; int dh = rem / 7, dw = rem - dh * 7;
  int t0 = (tw * 2 + dt + 1) & 7;                 // roll by shift (1,3,3)
  int h0 = hw * 7 + dh + 3; if (h0 >= 56) h0 -= 56;
  int w0 = ww * 7 + dw + 3; if (w0 >= 56) w0 -= 56;
  map[t] = ((b * 8 + t0) * 56 + h0) * 56 + w0;    // spatial row for window-token t
}

// packed bias in MFMA-fragment order: pb[h][mi][ni][lane][r], j>=98 mask pre-baked
__global__ __launch_bounds__(256) void expand_biasp_k(const float* __restrict__ table,
                                                      const int* __restrict__ rel,
                                                      float* __restrict__ out) {
  int e = blockIdx.x * 256 + threadIdx.x;
  if (e >= NHEADS * 49 * 256) return;
  int r = e & 3, l = (e >> 2) & 63;
  int rest = e >> 8;
  int ni = rest % 7, mi = (rest / 7) % 7, h = rest / 49;
  int i = mi * 16 + (l >> 4) * 4 + r;
  int j = ni * 16 + (l & 15);
  float v;
  if (j >= 98) v = -1e30f;          // pad-column mask baked in
  else if (i >= 98) v = 0.f;
  else v = table[rel[i * 98 + j] * NHEADS + h];
  out[e] = v;
}

__global__ __launch_bounds__(256) void transpose_w_k(const float* __restrict__ W,
                                                     __bf16* __restrict__ WT,
                                                     int K, int N, int scaleCols, float scale) {
  int e = blockIdx.x * 256 + threadIdx.x;
  if (e >= K * N) return;
  int n = e / K, k = e - n * K;
  float v = W[(size_t)k * N + n];
  if (n < scaleCols) v *= scale;                  // fold q-scale into W_q
  WT[e] = (__bf16)v;                              // WT[n][k]
}

__global__ __launch_bounds__(256) void scale_bias_k(const float* __restrict__ b,
                                                    float* __restrict__ out,
                                                    int n, int scaleCols, float scale) {
  int e = blockIdx.x * 256 + threadIdx.x;
  if (e >= n) return;
  out[e] = b[e] * (e < scaleCols ? scale : 1.0f);
}

// V^T: vt[(win*12+h)*32 + d][tok 0..127] bf16, zeros past tok 97
__global__ __launch_bounds__(384) void vtrans_k(const __bf16* __restrict__ qkv,
                                                __bf16* __restrict__ vt) {
  int win = blockIdx.x, t = threadIdx.x;          // t = h*32+d
  const __bf16* base = qkv + (size_t)win * 98 * QKV_DIM + 768 + t;
  __bf16* orow = vt + ((size_t)win * 384 + t) * 128;
  #pragma unroll
  for (int c = 0; c < 16; ++c) {
    bf16x8 pk;
    #pragma unroll
    for (int e2 = 0; e2 < 8; ++e2) {
      int tok = c * 8 + e2;
      pk[e2] = (tok < 98) ? base[(size_t)tok * QKV_DIM] : (__bf16)0.f;
    }
    *(bf16x8*)(orow + c * 8) = pk;
  }
}

// ---------------- layernorm (1 wave per token row of 384) ----------------
__global__ __launch_bounds__(256) void ln_k(const float* __restrict__ x,
                                            const float* __restrict__ g,
                                            const float* __restrict__ bta,
                                            __bf16* __restrict__ out,
                                            const int* __restrict__ map) {
  int w = threadIdx.x >> 6, l = threadIdx.x & 63;
  int tok = blockIdx.x * 4 + w;
  int src = map ? map[tok] : tok;
  const float* row = x + (size_t)src * DIM;
  float v[6]; float s = 0.f;
  #pragma unroll
  for (int j = 0; j < 6; ++j) { v[j] = row[l + 64 * j]; s += v[j]; }
  #pragma unroll
  for (int m = 1; m < 64; m <<= 1) s += __shfl_xor(s, m, 64);
  float mu = s * (1.f / DIM);
  float var = 0.f;
  #pragma unroll
  for (int j = 0; j < 6; ++j) { float d = v[j] - mu; var += d * d; }
  #pragma unroll
  for (int m = 1; m < 64; m <<= 1) var += __shfl_xor(var, m, 64);
  float rs = rsqrtf(var * (1.f / DIM) + 1e-5f);
  __bf16* orow = out + (size_t)tok * DIM;
  #pragma unroll
  for (int j = 0; j < 6; ++j) {
    int c = l + 64 * j;
    orow[c] = (__bf16)((v[j] - mu) * rs * g[c] + bta[c]);
  }
}

// ---------------- 128x128 bf16 MFMA GEMM, BK=64, 4 waves, direct-B ----------
// A[M][K] bf16 staged to LDS (16KB dbuf, XOR-swizzled via pre-swizzled global
// source); B = WT[N][K] read directly from global (L2-resident weights).
// Per iter: [8 B-loads][4 A-stages(kt+1)][vmcnt(12): A(kt) done, 12 newer in
// flight][barrier][ds_read A, MFMA (compiler waits B at vmcnt(4))][barrier].
// Operands swapped in MFMA -> C^T fragments -> vectorized epilogue.
// EPI: 0 = +bias -> bf16   1 = +bias, scatter via tokmap, +resid -> fp32
//      2 = +bias, fast-gelu -> bf16   3 = +bias, +resid -> fp32 (linear)
template <int EPI>
__global__ __launch_bounds__(256, 3) void gemm_k(const __bf16* __restrict__ A,
                                                 const __bf16* __restrict__ BT,
                                                 const float* __restrict__ bias,
                                                 int M, int N, int K,
                                                 __bf16* __restrict__ outb,
                                                 float* __restrict__ outf,
                                                 const float* __restrict__ resid,
                                                 const int* __restrict__ tokmap) {
  __shared__ __align__(1024) char lds[32768];     // 2 x A 16KB
  const int tid = threadIdx.x;
  const int l = tid & 63, w = tid >> 6;
  const int lr = l & 15, lg = l >> 4;
  const int ntile = N >> 7;
  // XCD chunking: contiguous run of bids per XCD (all grids divisible by 8)
  const int nwg8 = gridDim.x >> 3;
  const int bid = (blockIdx.x & 7) * nwg8 + (blockIdx.x >> 3);
  const int bm = bid / ntile, bn = bid - bm * ntile;
  const int m0 = bm << 7, n0 = bn << 7;
  const int wr = w >> 1, wc = w & 1;
  // A staging: lane covers row (l>>3) of an 8-row group; source chunk pre-swizzled
  const int srow = l >> 3;
  const int sch = (l & 7) ^ srow;
  const __bf16* pa = A + (size_t)(m0 + w * 32 + srow) * K + sch * 8;
  const int doff = w * 4096;                      // wave's 32-row staging region
  const int nk = K >> 6;
  // B row bases (per-lane): row = n0 + wc*64 + n*16 + lr, k base = lg*8
  const __bf16* pbn[4];
  #pragma unroll
  for (int n = 0; n < 4; ++n)
    pbn[n] = BT + (size_t)(n0 + (wc << 6) + (n << 4) + lr) * K + lg * 8;

  // prologue: A tile 0 -> buffer 0
  #pragma unroll
  for (int i = 0; i < 4; ++i)
    gload16(pa + (size_t)(i * 8) * K, lds + doff + i * 1024);

  f32x4 acc[4][4] = {};
  for (int kt = 0; kt < nk; ++kt) {
    const char* cur = lds + ((kt & 1) << 14);
    // B-frags for this tile: direct global (L1/L2-served), counted by compiler
    bf16x8 bfr[4][2];
    #pragma unroll
    for (int n = 0; n < 4; ++n) {
      bfr[n][0] = *(const bf16x8*)(pbn[n] + (kt << 6));
      bfr[n][1] = *(const bf16x8*)(pbn[n] + (kt << 6) + 32);
    }
    if (kt + 1 < nk) {
      char* nxt = lds + (((kt + 1) & 1) << 14);
      const size_t koff = (size_t)(kt + 1) << 6;
      #pragma unroll
      for (int i = 0; i < 4; ++i)
        gload16(pa + (size_t)(i * 8) * K + koff, nxt + doff + i * 1024);
      // oldest 4 = A(kt) stages; 8 B + 4 A(kt+1) stay in flight
      asm volatile("s_waitcnt vmcnt(12)" ::: "memory");
    } else {
      asm volatile("s_waitcnt vmcnt(8)" ::: "memory");   // only 8 B newer
    }
    asm volatile("s_barrier" ::: "memory");              // all waves' A(kt) DMA done
    #pragma unroll
    for (int kk = 0; kk < 2; ++kk) {
      bf16x8 af[4];
      const int ck = (kk << 2) + lg;
      #pragma unroll
      for (int m = 0; m < 4; ++m) {
        int r = (wr << 6) + (m << 4) + lr;
        af[m] = *(const bf16x8*)(cur + (r << 7) + ((ck ^ (r & 7)) << 4));
      }
      #pragma unroll
      for (int m = 0; m < 4; ++m)
        #pragma unroll
        for (int n = 0; n < 4; ++n)   // swapped operands -> C^T fragment layout
          acc[m][n] = __builtin_amdgcn_mfma_f32_16x16x32_bf16(bfr[n][kk], af[m], acc[m][n], 0, 0, 0);
    }
    asm volatile("s_barrier" ::: "memory");  // LDS reads done before buffer re-staged
  }

  // epilogue (C^T frags): row = m0+wr*64+m*16+lr, cols = n0+wc*64+n*16+lg*4 .. +3
  #pragma unroll
  for (int m = 0; m < 4; ++m) {
    const int grow = m0 + (wr << 6) + (m << 4) + lr;
    #pragma unroll
    for (int n = 0; n < 4; ++n) {
      const int gcol = n0 + (wc << 6) + (n << 4) + (lg << 2);
      f32x4 a = acc[m][n] + *(const f32x4*)(bias + gcol);
      if (EPI == 0) {
        bf16x4 c;
        #pragma unroll
        for (int r = 0; r < 4; ++r) c[r] = (__bf16)a[r];
        *(bf16x4*)(outb + (size_t)grow * N + gcol) = c;
      } else if (EPI == 1) {
        int dst = tokmap[grow];
        f32x4 rv = *(const f32x4*)(resid + (size_t)dst * DIM + gcol);
        *(f32x4*)(outf + (size_t)dst * DIM + gcol) = rv + a;
      } else if (EPI == 2) {
        bf16x4 c;
        #pragma unroll
        for (int r = 0; r < 4; ++r) {
          float vv = a[r];
          float y = vv * (1.0f + 0.044715f * vv * vv);
          c[r] = (__bf16)(vv / (1.0f + __expf(-1.5957691216057308f * y)));
        }
        *(bf16x4*)(outb + (size_t)grow * N + gcol) = c;
      } else {
        f32x4 rv = *(const f32x4*)(resid + (size_t)grow * N + gcol);
        *(f32x4*)(outf + (size_t)grow * N + gcol) = rv + a;
      }
    }
  }
}

// ---------------- window attention: 1 wave per (window, head, mi-tile) ------
__global__ __launch_bounds__(64) void attn_k(const __bf16* __restrict__ qkv,
                                             const __bf16* __restrict__ vt,
                                             const float* __restrict__ pb,
                                             __bf16* __restrict__ out) {
  __shared__ __align__(1024) char P[4096];
  const int l = threadIdx.x, lr = l & 15, lg = l >> 4;
  const int bid = blockIdx.x;
  const int xc = bid & 7, kk = bid >> 3;
  const int wh = (kk / 7) * 8 + xc, mi = kk % 7;
  const int win = wh / NHEADS, h = wh - win * NHEADS;
  const size_t wbase = (size_t)win * 98 * QKV_DIM;
  const __bf16* qb = qkv + wbase + h * 32;
  const __bf16* kb = qb + 384;
  const bf16x8 z8 = {};
  const f32x4 fz = {};

  bf16x8 kf[7];
  #pragma unroll
  for (int ni = 0; ni < 7; ++ni) {
    int tok = ni * 16 + lr;
    kf[ni] = (tok < 98) ? *(const bf16x8*)(kb + (size_t)tok * QKV_DIM + lg * 8) : z8;
  }
  int qt = mi * 16 + lr;
  bf16x8 qf = (qt < 98) ? *(const bf16x8*)(qb + (size_t)qt * QKV_DIM + lg * 8) : z8;
  const f32x4* pbp = (const f32x4*)pb + (size_t)((h * 7 + mi) * 7) * 64 + l;
  f32x4 bv[7];
  #pragma unroll
  for (int ni = 0; ni < 7; ++ni) bv[ni] = pbp[ni * 64];

  f32x4 s[7];
  #pragma unroll
  for (int ni = 0; ni < 7; ++ni)
    s[ni] = __builtin_amdgcn_mfma_f32_16x16x32_bf16(qf, kf[ni], fz, 0, 0, 0);

  if (l < 32) {
    int row = l >> 1, c = 14 + (l & 1);
    *(f32x4*)(P + row * 256 + ((c ^ (row & 7)) << 4)) = fz;
  }

  #pragma unroll
  for (int r = 0; r < 4; ++r) {
    float mx = -1e30f;
    #pragma unroll
    for (int ni = 0; ni < 7; ++ni) {
      float vv = s[ni][r] + bv[ni][r];
      s[ni][r] = vv;
      mx = fmaxf(mx, vv);
    }
    #pragma unroll
    for (int m2 = 1; m2 < 16; m2 <<= 1) mx = fmaxf(mx, __shfl_xor(mx, m2, 64));
    float sum = 0.f;
    #pragma unroll
    for (int ni = 0; ni < 7; ++ni) { float p = __expf(s[ni][r] - mx); s[ni][r] = p; sum += p; }
    #pragma unroll
    for (int m2 = 1; m2 < 16; m2 <<= 1) sum += __shfl_xor(sum, m2, 64);
    float inv = 1.0f / sum;
    int il = lg * 4 + r;
    #pragma unroll
    for (int ni = 0; ni < 7; ++ni) {
      int j = ni * 16 + lr;
      *(__bf16*)(P + il * 256 + (((j >> 3) ^ (il & 7)) << 4) + ((j & 7) << 1)) =
          (__bf16)(s[ni][r] * inv);
    }
  }
  __syncthreads();

  bf16x8 pa[4];
  #pragma unroll
  for (int ks = 0; ks < 4; ++ks) {
    int ck = ks * 4 + lg;
    pa[ks] = *(const bf16x8*)(P + lr * 256 + ((ck ^ (lr & 7)) << 4));
  }
  const __bf16* vrow = vt + ((size_t)wh * 32) * 128;
  __bf16* ob = out + ((size_t)win * 98 + mi * 16) * DIM + h * 32;
  #pragma unroll
  for (int nf = 0; nf < 2; ++nf) {
    int d = nf * 16 + lr;
    f32x4 o = fz;
    #pragma unroll
    for (int ks = 0; ks < 4; ++ks) {
      bf16x8 vb = *(const bf16x8*)(vrow + (size_t)d * 128 + ks * 32 + lg * 8);
      o = __builtin_amdgcn_mfma_f32_16x16x32_bf16(pa[ks], vb, o, 0, 0, 0);
    }
    #pragma unroll
    for (int r = 0; r < 4; ++r) {
      int il = lg * 4 + r;
      if (mi * 16 + il < 98) ob[(size_t)il * DIM + nf * 16 + lr] = (__bf16)o[r];
    }
  }
}

// ---------------- launch ----------------
extern "C" void kernel_launch(void* const* d_in, const int* in_sizes, int n_in,
                              void* d_out, int out_size, void* d_ws, size_t ws_size,
                              hipStream_t stream) {
  const float* x      = (const float*)d_in[0];
  const float* n1g    = (const float*)d_in[1];
  const float* n1b    = (const float*)d_in[2];
  const float* qkv_w  = (const float*)d_in[3];
  const float* qkv_b  = (const float*)d_in[4];
  const float* proj_w = (const float*)d_in[5];
  const float* proj_b = (const float*)d_in[6];
  const float* btab   = (const float*)d_in[7];
  const float* n2g    = (const float*)d_in[8];
  const float* n2b    = (const float*)d_in[9];
  const float* fc1_w  = (const float*)d_in[10];
  const float* fc1_b  = (const float*)d_in[11];
  const float* fc2_w  = (const float*)d_in[12];
  const float* fc2_b  = (const float*)d_in[13];
  const int*   relidx = (const int*)d_in[14];
  float* outp = (float*)d_out;
  (void)in_sizes; (void)n_in; (void)out_size; (void)ws_size;

  char* ws = (char*)d_ws;
  size_t off = 0;
  auto alloc = [&](size_t bytes) {
    char* p = ws + off;
    off = (off + bytes + 255) & ~(size_t)255;
    return p;
  };
  int*    tokmap = (int*)alloc((size_t)NTOK * 4);
  float*  biasex = (float*)alloc((size_t)NHEADS * 49 * 256 * 4);
  __bf16* wqkvT  = (__bf16*)alloc((size_t)QKV_DIM * DIM * 2);
  __bf16* wprojT = (__bf16*)alloc((size_t)DIM * DIM * 2);
  __bf16* wfc1T  = (__bf16*)alloc((size_t)HID * DIM * 2);
  __bf16* wfc2T  = (__bf16*)alloc((size_t)DIM * HID * 2);
  float*  qkvbS  = (float*)alloc((size_t)QKV_DIM * 4);
  __bf16* tokens = (__bf16*)alloc((size_t)NTOK * DIM * 2);   // LN1 out / attn out / LN2 out
  __bf16* qkvbuf = (__bf16*)alloc((size_t)NTOK * HID * 2);   // qkv (1152) then h1 (1536)
  __bf16* attnout = tokens;
  __bf16* h1 = qkvbuf;
  // vt (50.3MB) lives in d_out (77MB fp32) — proj overwrites d_out afterwards
  __bf16* vt = (__bf16*)d_out;

  const float scale = 0.17677669529663687f;  // 1/sqrt(32)

  build_tokmap_k<<<NTOK / 256, 256, 0, stream>>>(tokmap);
  expand_biasp_k<<<(NHEADS * 49 * 256) / 256, 256, 0, stream>>>(btab, relidx, biasex);
  transpose_w_k<<<(DIM * QKV_DIM) / 256, 256, 0, stream>>>(qkv_w, wqkvT, DIM, QKV_DIM, DIM, scale);
  transpose_w_k<<<(DIM * DIM) / 256, 256, 0, stream>>>(proj_w, wprojT, DIM, DIM, 0, 1.0f);
  transpose_w_k<<<(DIM * HID) / 256, 256, 0, stream>>>(fc1_w, wfc1T, DIM, HID, 0, 1.0f);
  transpose_w_k<<<(HID * DIM) / 256, 256, 0, stream>>>(fc2_w, wfc2T, HID, DIM, 0, 1.0f);
  scale_bias_k<<<(QKV_DIM + 255) / 256, 256, 0, stream>>>(qkv_b, qkvbS, QKV_DIM, DIM, scale);

  ln_k<<<NTOK / 4, 256, 0, stream>>>(x, n1g, n1b, tokens, tokmap);
  gemm_k<0><<<(NTOK / 128) * (QKV_DIM / 128), 256, 0, stream>>>(
      tokens, wqkvT, qkvbS, NTOK, QKV_DIM, DIM, qkvbuf, nullptr, nullptr, nullptr);
  vtrans_k<<<NWIN, 384, 0, stream>>>(qkvbuf, vt);
  attn_k<<<NWIN * NHEADS * 7, 64, 0, stream>>>(qkvbuf, vt, biasex, attnout);
  gemm_k<1><<<(NTOK / 128) * (DIM / 128), 256, 0, stream>>>(
      attnout, wprojT, proj_b, NTOK, DIM, DIM, nullptr, outp, x, tokmap);
  ln_k<<<NTOK / 4, 256, 0, stream>>>(outp, n2g, n2b, tokens, nullptr);
  gemm_k<2><<<(NTOK / 128) * (HID / 128), 256, 0, stream>>>(
      tokens, wfc1T, fc1_b, NTOK, HID, DIM, h1, nullptr, nullptr, nullptr);
  gemm_k<3><<<(NTOK / 128) * (DIM / 128), 256, 0, stream>>>(
      h1, wfc2T, fc2_b, NTOK, DIM, HID, nullptr, outp, outp, nullptr);
}

// Round 7
// 504.778 us; speedup vs baseline: 1.2904x; 1.2904x over previous
//
#include <hip/hip_runtime.h>
#include <cstdint>
#include <cstddef>

// SwinBlock3D: LN1 -> roll(-1,-3,-3) -> window(2,7,7) attn (12 heads, rel-bias)
// -> proj + resid -> LN2 -> MLP(384->1536 gelu ->384) + resid.
// bf16 MFMA matmuls; fp32 LN/softmax/final residual; bf16 s1 intermediate.
// GEMM v3: A staged via global_load_lds (16KB dbuf, counted vmcnt, R4-proven);
// B PRE-PACKED into fragment-stream order -> direct coalesced L2 reads
// (fixes R6's lane-scattered direct-B), reg double-buffered 1 K-tile ahead.

typedef __bf16 bf16x8 __attribute__((ext_vector_type(8)));
typedef __bf16 bf16x4 __attribute__((ext_vector_type(4)));
typedef float f32x4 __attribute__((ext_vector_type(4)));

#define DIM 384
#define QKV_DIM 1152
#define HID 1536
#define NHEADS 12
#define NTOK 50176
#define NWIN 512

// async global->LDS, 16B per lane; LDS dest = wave-uniform base + lane*16
__device__ __forceinline__ void gload16(const void* g, void* s) {
  __builtin_amdgcn_global_load_lds(
      (const __attribute__((address_space(1))) void*)g,
      (__attribute__((address_space(3))) void*)s, 16, 0, 0);
}

// ---------------- prep kernels ----------------
__global__ __launch_bounds__(256) void build_tokmap_k(int* __restrict__ map) {
  int t = blockIdx.x * 256 + threadIdx.x;
  if (t >= NTOK) return;
  int win = t / 98, n = t - win * 98;
  int b = win >> 8, tw = (win >> 6) & 3, hw = (win >> 3) & 7, ww = win & 7;
  int dt = n / 49; int rem = n - dt * 49; int dh = rem / 7, dw = rem - dh * 7;
  int t0 = (tw * 2 + dt + 1) & 7;                 // roll by shift (1,3,3)
  int h0 = hw * 7 + dh + 3; if (h0 >= 56) h0 -= 56;
  int w0 = ww * 7 + dw + 3; if (w0 >= 56) w0 -= 56;
  map[t] = ((b * 8 + t0) * 56 + h0) * 56 + w0;    // spatial row for window-token t
}

// packed bias in MFMA-fragment order: pb[h][mi][ni][lane][r], j>=98 mask pre-baked
__global__ __launch_bounds__(256) void expand_biasp_k(const float* __restrict__ table,
                                                      const int* __restrict__ rel,
                                                      float* __restrict__ out) {
  int e = blockIdx.x * 256 + threadIdx.x;
  if (e >= NHEADS * 49 * 256) return;
  int r = e & 3, l = (e >> 2) & 63;
  int rest = e >> 8;
  int ni = rest % 7, mi = (rest / 7) % 7, h = rest / 49;
  int i = mi * 16 + (l >> 4) * 4 + r;
  int j = ni * 16 + (l & 15);
  float v;
  if (j >= 98) v = -1e30f;          // pad-column mask baked in
  else if (i >= 98) v = 0.f;
  else v = table[rel[i * 98 + j] * NHEADS + h];
  out[e] = v;
}

// Pack W[K][N] -> fragment-stream: chunk idx = (((bn*nk+kt)*2+wc)*8 + n*2+kk)*64 + l
// holds BT[bn*128+wc*64+n*16+(l&15)][kt*64+((kk*4)+(l>>4))*8 .. +8].
// In-kernel B-load = wave-uniform base + l*16B -> perfectly coalesced 1KB chunks.
__global__ __launch_bounds__(256) void pack_w_k(const float* __restrict__ W,
                                                __bf16* __restrict__ WP,
                                                int K, int N, int nk,
                                                int scaleCols, float scale) {
  int idx = blockIdx.x * 256 + threadIdx.x;
  if (idx >= (K * N) >> 3) return;
  int l = idx & 63, f = (idx >> 6) & 7, wc = (idx >> 9) & 1;
  int rest = idx >> 10, kt = rest % nk, bn = rest / nk;
  int n = f >> 1, kk = f & 1;
  int row = bn * 128 + wc * 64 + n * 16 + (l & 15);
  int k0 = kt * 64 + (kk * 4 + (l >> 4)) * 8;
  float sc = (row < scaleCols) ? scale : 1.0f;
  bf16x8 v;
  #pragma unroll
  for (int j = 0; j < 8; ++j)
    v[j] = (__bf16)(W[(size_t)(k0 + j) * N + row] * sc);
  *(bf16x8*)(WP + (size_t)idx * 8) = v;
}

__global__ __launch_bounds__(256) void scale_bias_k(const float* __restrict__ b,
                                                    float* __restrict__ out,
                                                    int n, int scaleCols, float scale) {
  int e = blockIdx.x * 256 + threadIdx.x;
  if (e >= n) return;
  out[e] = b[e] * (e < scaleCols ? scale : 1.0f);
}

// V^T: vt[(win*12+h)*32 + d][tok 0..127] bf16, zeros past tok 97
__global__ __launch_bounds__(384) void vtrans_k(const __bf16* __restrict__ qkv,
                                                __bf16* __restrict__ vt) {
  int win = blockIdx.x, t = threadIdx.x;          // t = h*32+d
  const __bf16* base = qkv + (size_t)win * 98 * QKV_DIM + 768 + t;
  __bf16* orow = vt + ((size_t)win * 384 + t) * 128;
  #pragma unroll
  for (int c = 0; c < 16; ++c) {
    bf16x8 pk;
    #pragma unroll
    for (int e2 = 0; e2 < 8; ++e2) {
      int tok = c * 8 + e2;
      pk[e2] = (tok < 98) ? base[(size_t)tok * QKV_DIM] : (__bf16)0.f;
    }
    *(bf16x8*)(orow + c * 8) = pk;
  }
}

// ---------------- layernorm (1 wave per token row of 384) ----------------
template <typename T>
__global__ __launch_bounds__(256) void ln_k(const T* __restrict__ x,
                                            const float* __restrict__ g,
                                            const float* __restrict__ bta,
                                            __bf16* __restrict__ out,
                                            const int* __restrict__ map) {
  int w = threadIdx.x >> 6, l = threadIdx.x & 63;
  int tok = blockIdx.x * 4 + w;
  int src = map ? map[tok] : tok;
  const T* row = x + (size_t)src * DIM;
  float v[6]; float s = 0.f;
  #pragma unroll
  for (int j = 0; j < 6; ++j) { v[j] = (float)row[l + 64 * j]; s += v[j]; }
  #pragma unroll
  for (int m = 1; m < 64; m <<= 1) s += __shfl_xor(s, m, 64);
  float mu = s * (1.f / DIM);
  float var = 0.f;
  #pragma unroll
  for (int j = 0; j < 6; ++j) { float d = v[j] - mu; var += d * d; }
  #pragma unroll
  for (int m = 1; m < 64; m <<= 1) var += __shfl_xor(var, m, 64);
  float rs = rsqrtf(var * (1.f / DIM) + 1e-5f);
  __bf16* orow = out + (size_t)tok * DIM;
  #pragma unroll
  for (int j = 0; j < 6; ++j) {
    int c = l + 64 * j;
    orow[c] = (__bf16)((v[j] - mu) * rs * g[c] + bta[c]);
  }
}

// ---------------- 128x128 bf16 MFMA GEMM, BK=64, 4 waves, packed-B ----------
// A[M][K] staged to LDS (16KB dbuf, XOR-swizzled, global_load_lds); B read as
// coalesced packed fragment stream into regs, double-buffered 1 K-tile ahead.
// Per iter: [8 B-loads(kt+1)][4 A-stages(kt+1)][vmcnt(12): A(kt)+B(kt) done,
// 12 newer in flight][barrier][8 ds_read A + 32 MFMA][barrier].
// MFMA operands swapped -> C^T fragments -> vectorized epilogue.
// EPI: 0 = +bias -> bf16   1 = +bias + residf(x), scatter tokmap -> bf16 (s1)
//      2 = +bias, fast-gelu -> bf16   3 = +bias + residb(s1) -> fp32 (linear)
template <int EPI>
__global__ __launch_bounds__(256, 2) void gemm_k(const __bf16* __restrict__ A,
                                                 const __bf16* __restrict__ WP,
                                                 const float* __restrict__ bias,
                                                 int M, int N, int K,
                                                 __bf16* __restrict__ outb,
                                                 float* __restrict__ outf,
                                                 const float* __restrict__ residf,
                                                 const __bf16* __restrict__ residb,
                                                 const int* __restrict__ tokmap) {
  __shared__ __align__(1024) char lds[32768];     // 2 x A 16KB
  const int tid = threadIdx.x;
  const int l = tid & 63, w = tid >> 6;
  const int lr = l & 15, lg = l >> 4;
  const int ntile = N >> 7;
  // XCD chunking: contiguous run of bids per XCD (all grids divisible by 8)
  const int nwg8 = gridDim.x >> 3;
  const int bid = (blockIdx.x & 7) * nwg8 + (blockIdx.x >> 3);
  const int bm = bid / ntile, bn = bid - bm * ntile;
  const int m0 = bm << 7, n0 = bn << 7;
  const int wr = w >> 1, wc = w & 1;
  // A staging: lane covers row (l>>3) of an 8-row group; source chunk pre-swizzled
  const int srow = l >> 3;
  const int sch = (l & 7) ^ srow;
  const __bf16* pa = A + (size_t)(m0 + w * 32 + srow) * K + sch * 8;
  const int doff = w * 4096;                      // wave's 32-row staging region
  const int nk = K >> 6;
  // packed-B lane base: frag f at tile kt = pB + kt*8192 + f*512
  const __bf16* pB = WP + ((size_t)bn * nk * 2 + wc) * 4096 + l * 8;

#define LOADB(dst, ktl)                                        \
  {                                                            \
    const __bf16* p_ = pB + (size_t)(ktl) * 8192;              \
    _Pragma("unroll")                                          \
    for (int f_ = 0; f_ < 8; ++f_)                             \
      dst[f_] = *(const bf16x8*)(p_ + f_ * 512);               \
  }

  // prologue: B(0) + A(0); invariant at iter entry: B(kt)8 then A(kt)4 in flight
  bf16x8 b0[8], b1[8];
  LOADB(b0, 0);
  #pragma unroll
  for (int i = 0; i < 4; ++i)
    gload16(pa + (size_t)(i * 8) * K, lds + doff + i * 1024);

  f32x4 acc[4][4] = {};

  auto iter = [&](int kt, bf16x8 (&bc)[8], bf16x8 (&bnx)[8]) {
    const char* cur = lds + ((kt & 1) << 14);
    if (kt + 1 < nk) {
      LOADB(bnx, kt + 1);
      char* nxt = lds + (((kt + 1) & 1) << 14);
      const size_t koff = (size_t)(kt + 1) << 6;
      #pragma unroll
      for (int i = 0; i < 4; ++i)
        gload16(pa + (size_t)(i * 8) * K + koff, nxt + doff + i * 1024);
      // newer-than-A(kt): 8 B(kt+1) + 4 A(kt+1); B(kt) is older -> also done
      asm volatile("s_waitcnt vmcnt(12)" ::: "memory");
    } else {
      asm volatile("s_waitcnt vmcnt(0)" ::: "memory");
    }
    asm volatile("s_barrier" ::: "memory");       // all waves' A(kt) DMA done
    #pragma unroll
    for (int kk = 0; kk < 2; ++kk) {
      bf16x8 af[4];
      const int ck = (kk << 2) + lg;
      #pragma unroll
      for (int m = 0; m < 4; ++m) {
        int r = (wr << 6) + (m << 4) + lr;
        af[m] = *(const bf16x8*)(cur + (r << 7) + ((ck ^ (r & 7)) << 4));
      }
      #pragma unroll
      for (int m = 0; m < 4; ++m)
        #pragma unroll
        for (int n = 0; n < 4; ++n)   // swapped operands -> C^T fragment layout
          acc[m][n] = __builtin_amdgcn_mfma_f32_16x16x32_bf16(bc[n * 2 + kk], af[m],
                                                              acc[m][n], 0, 0, 0);
    }
    asm volatile("s_barrier" ::: "memory");  // LDS reads done before re-stage
  };

  for (int kt = 0; kt < nk; kt += 2) {   // nk always even (6 or 24)
    iter(kt, b0, b1);
    iter(kt + 1, b1, b0);
  }
#undef LOADB

  // epilogue (C^T frags): row = m0+wr*64+m*16+lr, cols = n0+wc*64+n*16+lg*4..+3
  #pragma unroll
  for (int m = 0; m < 4; ++m) {
    const int grow = m0 + (wr << 6) + (m << 4) + lr;
    #pragma unroll
    for (int n = 0; n < 4; ++n) {
      const int gcol = n0 + (wc << 6) + (n << 4) + (lg << 2);
      f32x4 a = acc[m][n] + *(const f32x4*)(bias + gcol);
      if (EPI == 0) {
        bf16x4 c;
        #pragma unroll
        for (int r = 0; r < 4; ++r) c[r] = (__bf16)a[r];
        *(bf16x4*)(outb + (size_t)grow * N + gcol) = c;
      } else if (EPI == 1) {
        int dst = tokmap[grow];
        f32x4 rv = *(const f32x4*)(residf + (size_t)dst * DIM + gcol);
        bf16x4 c;
        #pragma unroll
        for (int r = 0; r < 4; ++r) c[r] = (__bf16)(rv[r] + a[r]);
        *(bf16x4*)(outb + (size_t)dst * DIM + gcol) = c;
      } else if (EPI == 2) {
        bf16x4 c;
        #pragma unroll
        for (int r = 0; r < 4; ++r) {
          float vv = a[r];
          float y = vv * (1.0f + 0.044715f * vv * vv);
          c[r] = (__bf16)(vv / (1.0f + __expf(-1.5957691216057308f * y)));
        }
        *(bf16x4*)(outb + (size_t)grow * N + gcol) = c;
      } else {
        bf16x4 sv = *(const bf16x4*)(residb + (size_t)grow * N + gcol);
        f32x4 o;
        #pragma unroll
        for (int r = 0; r < 4; ++r) o[r] = (float)sv[r] + a[r];
        *(f32x4*)(outf + (size_t)grow * N + gcol) = o;
      }
    }
  }
}

// ---------------- window attention: 1 wave per (window, head, mi-tile) ------
__global__ __launch_bounds__(64) void attn_k(const __bf16* __restrict__ qkv,
                                             const __bf16* __restrict__ vt,
                                             const float* __restrict__ pb,
                                             __bf16* __restrict__ out) {
  __shared__ __align__(1024) char P[4096];
  const int l = threadIdx.x, lr = l & 15, lg = l >> 4;
  const int bid = blockIdx.x;
  const int xc = bid & 7, kk = bid >> 3;
  const int wh = (kk / 7) * 8 + xc, mi = kk % 7;
  const int win = wh / NHEADS, h = wh - win * NHEADS;
  const size_t wbase = (size_t)win * 98 * QKV_DIM;
  const __bf16* qb = qkv + wbase + h * 32;
  const __bf16* kb = qb + 384;
  const bf16x8 z8 = {};
  const f32x4 fz = {};

  bf16x8 kf[7];
  #pragma unroll
  for (int ni = 0; ni < 7; ++ni) {
    int tok = ni * 16 + lr;
    kf[ni] = (tok < 98) ? *(const bf16x8*)(kb + (size_t)tok * QKV_DIM + lg * 8) : z8;
  }
  int qt = mi * 16 + lr;
  bf16x8 qf = (qt < 98) ? *(const bf16x8*)(qb + (size_t)qt * QKV_DIM + lg * 8) : z8;
  const f32x4* pbp = (const f32x4*)pb + (size_t)((h * 7 + mi) * 7) * 64 + l;
  f32x4 bv[7];
  #pragma unroll
  for (int ni = 0; ni < 7; ++ni) bv[ni] = pbp[ni * 64];

  f32x4 s[7];
  #pragma unroll
  for (int ni = 0; ni < 7; ++ni)
    s[ni] = __builtin_amdgcn_mfma_f32_16x16x32_bf16(qf, kf[ni], fz, 0, 0, 0);

  if (l < 32) {
    int row = l >> 1, c = 14 + (l & 1);
    *(f32x4*)(P + row * 256 + ((c ^ (row & 7)) << 4)) = fz;
  }

  #pragma unroll
  for (int r = 0; r < 4; ++r) {
    float mx = -1e30f;
    #pragma unroll
    for (int ni = 0; ni < 7; ++ni) {
      float vv = s[ni][r] + bv[ni][r];
      s[ni][r] = vv;
      mx = fmaxf(mx, vv);
    }
    #pragma unroll
    for (int m2 = 1; m2 < 16; m2 <<= 1) mx = fmaxf(mx, __shfl_xor(mx, m2, 64));
    float sum = 0.f;
    #pragma unroll
    for (int ni = 0; ni < 7; ++ni) { float p = __expf(s[ni][r] - mx); s[ni][r] = p; sum += p; }
    #pragma unroll
    for (int m2 = 1; m2 < 16; m2 <<= 1) sum += __shfl_xor(sum, m2, 64);
    float inv = 1.0f / sum;
    int il = lg * 4 + r;
    #pragma unroll
    for (int ni = 0; ni < 7; ++ni) {
      int j = ni * 16 + lr;
      *(__bf16*)(P + il * 256 + (((j >> 3) ^ (il & 7)) << 4) + ((j & 7) << 1)) =
          (__bf16)(s[ni][r] * inv);
    }
  }
  __syncthreads();

  bf16x8 pa[4];
  #pragma unroll
  for (int ks = 0; ks < 4; ++ks) {
    int ck = ks * 4 + lg;
    pa[ks] = *(const bf16x8*)(P + lr * 256 + ((ck ^ (lr & 7)) << 4));
  }
  const __bf16* vrow = vt + ((size_t)wh * 32) * 128;
  __bf16* ob = out + ((size_t)win * 98 + mi * 16) * DIM + h * 32;
  #pragma unroll
  for (int nf = 0; nf < 2; ++nf) {
    int d = nf * 16 + lr;
    f32x4 o = fz;
    #pragma unroll
    for (int ks = 0; ks < 4; ++ks) {
      bf16x8 vb = *(const bf16x8*)(vrow + (size_t)d * 128 + ks * 32 + lg * 8);
      o = __builtin_amdgcn_mfma_f32_16x16x32_bf16(pa[ks], vb, o, 0, 0, 0);
    }
    #pragma unroll
    for (int r = 0; r < 4; ++r) {
      int il = lg * 4 + r;
      if (mi * 16 + il < 98) ob[(size_t)il * DIM + nf * 16 + lr] = (__bf16)o[r];
    }
  }
}

// ---------------- launch ----------------
extern "C" void kernel_launch(void* const* d_in, const int* in_sizes, int n_in,
                              void* d_out, int out_size, void* d_ws, size_t ws_size,
                              hipStream_t stream) {
  const float* x      = (const float*)d_in[0];
  const float* n1g    = (const float*)d_in[1];
  const float* n1b    = (const float*)d_in[2];
  const float* qkv_w  = (const float*)d_in[3];
  const float* qkv_b  = (const float*)d_in[4];
  const float* proj_w = (const float*)d_in[5];
  const float* proj_b = (const float*)d_in[6];
  const float* btab   = (const float*)d_in[7];
  const float* n2g    = (const float*)d_in[8];
  const float* n2b    = (const float*)d_in[9];
  const float* fc1_w  = (const float*)d_in[10];
  const float* fc1_b  = (const float*)d_in[11];
  const float* fc2_w  = (const float*)d_in[12];
  const float* fc2_b  = (const float*)d_in[13];
  const int*   relidx = (const int*)d_in[14];
  float* outp = (float*)d_out;
  (void)in_sizes; (void)n_in; (void)out_size; (void)ws_size;

  char* ws = (char*)d_ws;
  size_t off = 0;
  auto alloc = [&](size_t bytes) {
    char* p = ws + off;
    off = (off + bytes + 255) & ~(size_t)255;
    return p;
  };
  int*    tokmap = (int*)alloc((size_t)NTOK * 4);
  float*  biasex = (float*)alloc((size_t)NHEADS * 49 * 256 * 4);
  __bf16* wqkvP  = (__bf16*)alloc((size_t)QKV_DIM * DIM * 2);
  __bf16* wprojP = (__bf16*)alloc((size_t)DIM * DIM * 2);
  __bf16* wfc1P  = (__bf16*)alloc((size_t)HID * DIM * 2);
  __bf16* wfc2P  = (__bf16*)alloc((size_t)DIM * HID * 2);
  float*  qkvbS  = (float*)alloc((size_t)QKV_DIM * 4);
  __bf16* tokens = (__bf16*)alloc((size_t)NTOK * DIM * 2);   // LN1 out / attn out / LN2 out
  __bf16* qkvbuf = (__bf16*)alloc((size_t)NTOK * HID * 2);   // qkv (1152) then h1 (1536)
  __bf16* s1     = (__bf16*)alloc((size_t)NTOK * DIM * 2);   // x + attn-proj, bf16
  __bf16* attnout = tokens;
  __bf16* h1 = qkvbuf;
  // vt (50.3MB) lives in d_out (77MB fp32) — only fc2 writes d_out, at the end
  __bf16* vt = (__bf16*)d_out;

  const float scale = 0.17677669529663687f;  // 1/sqrt(32)

  build_tokmap_k<<<NTOK / 256, 256, 0, stream>>>(tokmap);
  expand_biasp_k<<<(NHEADS * 49 * 256) / 256, 256, 0, stream>>>(btab, relidx, biasex);
  pack_w_k<<<(DIM * QKV_DIM / 8) / 256, 256, 0, stream>>>(qkv_w, wqkvP, DIM, QKV_DIM, 6, DIM, scale);
  pack_w_k<<<(DIM * DIM / 8) / 256, 256, 0, stream>>>(proj_w, wprojP, DIM, DIM, 6, 0, 1.0f);
  pack_w_k<<<(DIM * HID / 8) / 256, 256, 0, stream>>>(fc1_w, wfc1P, DIM, HID, 6, 0, 1.0f);
  pack_w_k<<<(HID * DIM / 8) / 256, 256, 0, stream>>>(fc2_w, wfc2P, HID, DIM, 24, 0, 1.0f);
  scale_bias_k<<<(QKV_DIM + 255) / 256, 256, 0, stream>>>(qkv_b, qkvbS, QKV_DIM, DIM, scale);

  ln_k<float><<<NTOK / 4, 256, 0, stream>>>(x, n1g, n1b, tokens, tokmap);
  gemm_k<0><<<(NTOK / 128) * (QKV_DIM / 128), 256, 0, stream>>>(
      tokens, wqkvP, qkvbS, NTOK, QKV_DIM, DIM, qkvbuf, nullptr, nullptr, nullptr, nullptr);
  vtrans_k<<<NWIN, 384, 0, stream>>>(qkvbuf, vt);
  attn_k<<<NWIN * NHEADS * 7, 64, 0, stream>>>(qkvbuf, vt, biasex, attnout);
  gemm_k<1><<<(NTOK / 128) * (DIM / 128), 256, 0, stream>>>(
      attnout, wprojP, proj_b, NTOK, DIM, DIM, s1, nullptr, x, nullptr, tokmap);
  ln_k<__bf16><<<NTOK / 4, 256, 0, stream>>>(s1, n2g, n2b, tokens, nullptr);
  gemm_k<2><<<(NTOK / 128) * (HID / 128), 256, 0, stream>>>(
      tokens, wfc1P, fc1_b, NTOK, HID, DIM, h1, nullptr, nullptr, nullptr, nullptr);
  gemm_k<3><<<(NTOK / 128) * (DIM / 128), 256, 0, stream>>>(
      h1, wfc2P, fc2_b, NTOK, DIM, HID, nullptr, outp, nullptr, s1, nullptr);
}